// Round 14
// baseline (468.458 us; speedup 1.0000x reference)
//
#include <hip/hip_runtime.h>
#include <math.h>

// TreeAttention: N=16, T=S=2048, H=64, KS=64, INIT_W=16, 7 tree iterations.
// One wave per (n,t) row; 4 waves/block; wave-private LDS, no __syncthreads.
// Scoring: round-9 sequential-fma dot (bit-exact selection order).
// Ranking: shfl-bitonic sort + SHFL binary-search merge (no LDS search).
// V phase: cooperative 16-instr gather (4x fewer TA addresses).

constexpr int Tn = 2048;
constexpr int Hn = 64;
constexpr int WV = 4;
constexpr float NEGF = -1e9f;

typedef unsigned long long u64;
typedef unsigned int u32;

// wave-local LDS ordering: drain LDS ops + stop compiler reordering
#define WWAIT() asm volatile("s_waitcnt lgkmcnt(0)" ::: "memory")

__device__ __forceinline__ u32 ord32(float f) {
    u32 u = __float_as_uint(f);
    return (u & 0x80000000u) ? ~u : (u | 0x80000000u);
}
// total order: score desc, element index asc  (== jax.lax.top_k stable order)
__device__ __forceinline__ u64 packkey(float s, int e) {
    return ((u64)ord32(s) << 32) | (u64)(u32)(~e);
}
__device__ __forceinline__ float dec_score(u64 k) {
    u32 o = (u32)(k >> 32);
    u32 u = (o & 0x80000000u) ? (o & 0x7fffffffu) : ~o;
    return __uint_as_float(u);
}
__device__ __forceinline__ int dec_e(u64 k) { return (int)(~(u32)k); }

// pos = clip(round_half_even(z * ratio), 0, Tn-1); ratio=(t+1)/w2 exact fp32
__device__ __forceinline__ int cpos(int z, float ratio) {
    float x = (float)z * ratio;          // exact: z*(t+1) < 2^23
    int p = (int)rintf(x);               // v_rndne_f32 = half-to-even
    p = p < 0 ? 0 : p;
    p = p > (Tn - 1) ? (Tn - 1) : p;
    return p;
}

// round-9 sequential-fma dot: ONE chain in element order 0..63 -> equal-pos
// scores bit-identical; selections match reference (absmax 3.9e-3 measured).
__device__ __forceinline__ float dotq(const float* __restrict__ krow,
                                      const float* qs) {
    float acc = 0.f;
#pragma unroll
    for (int h = 0; h < Hn; h += 4) {
        float4 kv = *reinterpret_cast<const float4*>(krow + h);
        float4 qv = *reinterpret_cast<const float4*>(qs + h);
        acc = fmaf(qv.x, kv.x, acc);
        acc = fmaf(qv.y, kv.y, acc);
        acc = fmaf(qv.z, kv.z, acc);
        acc = fmaf(qv.w, kv.w, acc);
    }
    return acc;
}

// 64-bit xor-shuffle
__device__ __forceinline__ u64 shflx64(u64 v, int m) {
    u32 lo = (u32)__shfl_xor((int)(u32)v, m, 64);
    u32 hi = (u32)__shfl_xor((int)(v >> 32), m, 64);
    return ((u64)hi << 32) | lo;
}
// 64-bit variable-lane shuffle (ds_bpermute)
__device__ __forceinline__ u64 shflv64(u64 v, int idx) {
    u32 lo = (u32)__shfl((int)(u32)v, idx, 64);
    u32 hi = (u32)__shfl((int)(v >> 32), idx, 64);
    return ((u64)hi << 32) | lo;
}

// descending bitonic sort of one u64 key per lane over lanes 0..N-1
template<int N>
__device__ __forceinline__ u64 bitonic_desc(u64 key, int lane) {
#pragma unroll
    for (int k = 2; k <= N; k <<= 1) {
#pragma unroll
        for (int j = k >> 1; j >= 1; j >>= 1) {
            u64 pk = shflx64(key, j);
            bool wmax = (((lane & j) == 0) == ((lane & k) == 0));
            key = ((key > pk) == wmax) ? key : pk;
        }
    }
    return key;
}

// count of elements > x in the descending-sorted DISTRIBUTED list
// (lane i holds rank-i element in `dist`). Same compares as the LDS
// binary search it replaces -> identical counts.
template<int N>
__device__ __forceinline__ int cntgt(u64 dist, u64 x) {
    int c = 0;
#pragma unroll
    for (int s = N; s >= 1; s >>= 1) {
        int idx = c + s - 1;
        u64 pr = shflv64(dist, idx & 63);
        if (idx < N && pr > x) c += s;
    }
    return c;
}

__global__ void __launch_bounds__(256)
TreeAttention_70257075028607_kernel(
        const float* __restrict__ Q, const float* __restrict__ Kk,
        const float* __restrict__ V, float* __restrict__ O) {
    __shared__ __align__(16) float qsh[WV][Hn];
    __shared__ __align__(16) u64   Osh[WV][64];

    const int lane = threadIdx.x & 63;
    const int wv   = threadIdx.x >> 6;
    const int row  = blockIdx.x * WV + wv;      // n*T + t
    const int n    = row >> 11;
    const int t    = row & (Tn - 1);
    const float tp1 = (float)(t + 1);

    const float* qrow = Q + (size_t)row * Hn;
    const float* Kb   = Kk + (size_t)n * Tn * Hn;
    const float* Vb   = V  + (size_t)n * Tn * Hn;

    float* qs = qsh[wv];
    u64* Ob = Osh[wv];

    qs[lane] = qrow[lane];
    WWAIT();

    int   myz  = 0;
    float mysc = NEGF;

    // ---- iter 1: w2=32, cells z=0..31: score + register bitonic sort ----
    {
        const float ratio = tp1 * (1.f / 32.f);
        u64 key;
        if (lane < 32) {
            float s = dotq(Kb + (size_t)cpos(lane, ratio) * Hn, qs);
            key = packkey(s, lane);
        } else {
            key = (u64)lane;                     // inert filler, never crosses
        }
        key = bitonic_desc<32>(key, lane);
        if (lane < 32) { myz = dec_e(key); mysc = dec_score(key); }
    }

    // ---- iter 2: w2=64, 32 parents -> 64 children, keep all (sorted) ----
    {
        const float ratio = tp1 * (1.f / 64.f);
        u64 Lk = packkey(mysc, 2 * lane);        // parents sorted => L sorted
        u64 Rs;
        if (lane < 32) {
            float s1 = dotq(Kb + (size_t)cpos(2 * myz + 1, ratio) * Hn, qs);
            Rs = packkey(s1, 2 * lane + 1);
        } else {
            Rs = (u64)lane;
        }
        Rs = bitonic_desc<32>(Rs, lane);
        int rL = lane + cntgt<32>(Rs, Lk);       // merge ranks: perm of 0..63
        int rR = lane + cntgt<32>(Lk, Rs);
        if (lane < 32) {
            Ob[rL] = Lk;
            Ob[rR] = Rs;
        }
        WWAIT();
        u64 kk = Ob[lane];
        int e  = dec_e(kk);
        int pz = __shfl(myz, e >> 1, 64);
        myz  = 2 * pz + (e & 1);
        mysc = dec_score(kk);
    }

    // ---- iters 3..7: 64 parents -> 128 children, keep top-64 sorted ----
#pragma unroll
    for (int it = 0; it < 5; ++it) {
        const float ratio = tp1 * ldexpf(1.0f, -(7 + it));
        float s1 = dotq(Kb + (size_t)cpos(2 * myz + 1, ratio) * Hn, qs);
        u64 Lk = packkey(mysc, 2 * lane);        // sorted: parents in rank order
        u64 Rs = bitonic_desc<64>(packkey(s1, 2 * lane + 1), lane);
        int rL = lane + cntgt<64>(Rs, Lk);       // ranks: perm of 0..127
        int rR = lane + cntgt<64>(Lk, Rs);
        if (rL < 64) Ob[rL] = Lk;
        if (rR < 64) Ob[rR] = Rs;
        WWAIT();
        u64 kk = Ob[lane];
        int e  = dec_e(kk);
        int pz = __shfl(myz, e >> 1, 64);
        myz  = 2 * pz + (e & 1);
        mysc = dec_score(kk);
    }

    // ---- final: causal mask, softmax over 64, cooperative PV gather ----
    {
        int mypos  = cpos(myz, tp1 * (1.f / 2048.f));
        bool valid = ((float)mypos < tp1);
        float s = valid ? mysc * 0.125f : NEGF;  // / sqrt(64)

        float m = s;
#pragma unroll
        for (int off = 32; off >= 1; off >>= 1)
            m = fmaxf(m, __shfl_xor(m, off, 64));
        float p = expf(s - m);
        float sum = p;
#pragma unroll
        for (int off = 32; off >= 1; off >>= 1)
            sum += __shfl_xor(sum, off, 64);
        p = p / sum;
        if (!valid) p = 0.f;

        Ob[lane] = ((u64)(u32)mypos << 32) | __float_as_uint(p);
        WWAIT();

        // cooperative: lane = (cls = lane>>4 row-class, seg = lane&15).
        // 16 float4 loads/wave (4 rows per instr) instead of 64 full-row
        // instrs -> 4x fewer TA addresses on the V gather.
        const int seg = lane & 15;
        const int cls = lane >> 4;
        float ax = 0.f, ay = 0.f, az = 0.f, aw = 0.f;
#pragma unroll
        for (int i = 0; i < 16; ++i) {
            u64 w = Ob[i * 4 + cls];             // 4 distinct addrs, bcast x16
            float pj = __uint_as_float((u32)w);
            const float4 v = *reinterpret_cast<const float4*>(
                Vb + (size_t)(w >> 32) * Hn + seg * 4);
            ax = fmaf(pj, v.x, ax);
            ay = fmaf(pj, v.y, ay);
            az = fmaf(pj, v.z, az);
            aw = fmaf(pj, v.w, aw);
        }
        // reduce the 4 row-classes (lanes seg, seg+16, seg+32, seg+48)
        ax += __shfl_xor(ax, 16, 64); ay += __shfl_xor(ay, 16, 64);
        az += __shfl_xor(az, 16, 64); aw += __shfl_xor(aw, 16, 64);
        ax += __shfl_xor(ax, 32, 64); ay += __shfl_xor(ay, 32, 64);
        az += __shfl_xor(az, 32, 64); aw += __shfl_xor(aw, 32, 64);

        if (lane < 16) {
            float4 o4;
            o4.x = ax; o4.y = ay; o4.z = az; o4.w = aw;
            *reinterpret_cast<float4*>(O + (size_t)row * Hn + lane * 4) = o4;
        }
    }
}

extern "C" void kernel_launch(void* const* d_in, const int* in_sizes, int n_in,
                              void* d_out, int out_size, void* d_ws, size_t ws_size,
                              hipStream_t stream) {
    const float* Q = (const float*)d_in[0];
    const float* K = (const float*)d_in[1];
    const float* V = (const float*)d_in[2];
    float* O = (float*)d_out;

    const int rows = in_sizes[0] / Hn;   // N*T = 32768
    const int blocks = rows / WV;        // 8192
    TreeAttention_70257075028607_kernel<<<blocks, WV * 64, 0, stream>>>(Q, K, V, O);
}